// Round 20
// baseline (385.307 us; speedup 1.0000x reference)
//
#include <hip/hip_runtime.h>

#define C 16
#define NIMG 24
#define H 96
#define W 192
#define PX (H*W)            // 18432
#define LOG2E 1.44269504088896f

typedef float v2f  __attribute__((ext_vector_type(2)));
typedef float v4f  __attribute__((ext_vector_type(4)));
typedef short v8s  __attribute__((ext_vector_type(8)));

// workspace float offsets
#define QP_OFF 0                                // float2 [n][px]
#define KP_OFF (NIMG*PX*2)                      // float2 [n][px]
#define VB4_OFF (2*NIMG*PX*2)                   // ushort4 [n][h][c4][w] (bf16 x4ch)
#define VBP_OFF (VB4_OFF + NIMG*PX*C/2)         // ushort [n][h][c][w] (bf16 planar)
#define GM_OFF  (VBP_OFF + NIMG*PX*C/2)         // 8847360: float gmax [n][2]
#define SC_OFF  (GM_OFF + 128)                  // float s_col [n][h][w]
#define ACC_OFF (SC_OFF + NIMG*PX)              // ushort accC [n][h][w][c]
// end ~ 12.83M floats (~51.3 MB)

__device__ __forceinline__ unsigned short f2bf(float x) {
    union { float f; unsigned u; } v; v.f = x;
    unsigned r = v.u + 0x7fffu + ((v.u >> 16) & 1u);   // RNE
    return (unsigned short)(r >> 16);
}
__device__ __forceinline__ float bf2f(unsigned short u) {
    union { unsigned u; float f; } v; v.u = ((unsigned)u) << 16;
    return v.f;
}

__global__ __launch_bounds__(256)
void qkv_kernel(const float* __restrict__ x, long xn_s, long xc_s,
                const float* __restrict__ qw, const float* __restrict__ qb,
                const float* __restrict__ kw, const float* __restrict__ kb,
                const float* __restrict__ vw, const float* __restrict__ vb,
                float2* __restrict__ Qp, float2* __restrict__ Kp,
                ushort4* __restrict__ Vb4, unsigned short* __restrict__ Vbp,
                float* __restrict__ gm)
{
    __shared__ float wq[2*C+2], wk[2*C+2], wv[C*C+C];
    int tid = threadIdx.x;
    if (tid < 2*C) { wq[tid] = qw[tid]; wk[tid] = kw[tid]; }
    if (tid < 2)   { wq[2*C+tid] = qb[tid]; wk[2*C+tid] = kb[tid]; }
    if (tid < C*C) wv[tid] = vw[tid];
    if (tid < C)   wv[C*C+tid] = vb[tid];
    __syncthreads();

    int id = blockIdx.x*256 + tid;        // 0 .. 442367 (blocks never straddle n)
    int n  = id / PX;
    int p  = id - n*PX;
    int h  = p / W;
    int w  = p - h*W;
    const float* xp = x + (long)n*xn_s + p;

    float xv[C];
    #pragma unroll
    for (int c = 0; c < C; c++) xv[c] = xp[(long)c*xc_s];

    float q0 = wq[2*C], q1 = wq[2*C+1];
    float k0 = wk[2*C], k1 = wk[2*C+1];
    #pragma unroll
    for (int c = 0; c < C; c++) {
        q0 += wq[c]*xv[c];   q1 += wq[C+c]*xv[c];
        k0 += wk[c]*xv[c];   k1 += wk[C+c]*xv[c];
    }
    Qp[id] = make_float2(q0, q1);
    Kp[id] = make_float2(k0, k1);

    // per-image |K| maxima (2 scalars) for the softmax shift bound
    {
        float a0 = fabsf(k0), a1 = fabsf(k1);
        #pragma unroll
        for (int d = 1; d < 64; d <<= 1) {
            a0 = fmaxf(a0, __shfl_xor(a0, d));
            a1 = fmaxf(a1, __shfl_xor(a1, d));
        }
        if ((tid & 63) == 0) {
            atomicMax((unsigned*)&gm[n*2+0], __float_as_uint(a0));
            atomicMax((unsigned*)&gm[n*2+1], __float_as_uint(a1));
        }
    }

    float vv[C];
    #pragma unroll
    for (int o = 0; o < C; o++) {
        float a = wv[C*C+o];
        #pragma unroll
        for (int c = 0; c < C; c++) a += wv[o*C+c]*xv[c];
        vv[o] = a;
    }
    unsigned short vb16[C];
    #pragma unroll
    for (int o = 0; o < C; o++) vb16[o] = f2bf(vv[o]);

    // interleaved [n][h][c4][w] (ushort4) for col staging
    #pragma unroll
    for (int c4 = 0; c4 < 4; c4++) {
        ushort4 u;
        u.x = vb16[c4*4+0]; u.y = vb16[c4*4+1];
        u.z = vb16[c4*4+2]; u.w = vb16[c4*4+3];
        Vb4[(((long)n*H + h)*4 + c4)*W + w] = u;
    }
    // planar [n][h][c][w] for row fragment loads
    #pragma unroll
    for (int o = 0; o < C; o++)
        Vbp[(((long)n*H + h)*16 + o)*W + w] = vb16[o];
}

// Column (H) attention as MFMA (R18 structure, scalar shift bound).
#define VT_WS 1672   // per-w Vt stride in ushorts: 16*104 + 8 pad
__global__ __launch_bounds__(256)
void col_attn_kernel(const float2* __restrict__ Qp, const float2* __restrict__ Kp,
                     const ushort4* __restrict__ Vb4,
                     const float* __restrict__ gm,
                     unsigned short* __restrict__ accC, float* __restrict__ sC)
{
    __shared__ unsigned short Vt[4*VT_WS];      // V^T: [wl][c][j] bf16, j-pad 104
    __shared__ unsigned short Ks[4*2*96];       // K:   [wl][ch][j] bf16

    const int chunk = (NIMG*48) / 8;            // 144 ; 1152 % 8 == 0
    int bid = blockIdx.x;
    int swz = (bid & 7)*chunk + (bid >> 3);
    int n   = swz / 48;
    int wg  = swz - n*48;
    int w0  = wg*4;
    int tid = threadIdx.x;

    const float2* Qpn = Qp + n*PX;
    const float2* Kpn = Kp + n*PX;
    const ushort4* Vbn = Vb4 + (long)n*PX*4;
    float g0 = gm[n*2+0], g1 = gm[n*2+1];

    // ---- stage V^T (1536 ushort4, 6/thread) ----
    #pragma unroll
    for (int i = 0; i < 6; i++) {
        int idx = i*256 + tid;        // 0..1535
        int wl  = idx & 3;
        int c4  = (idx >> 2) & 3;
        int j   = idx >> 4;           // 0..95
        ushort4 v = Vbn[((long)j*4 + c4)*W + w0 + wl];
        int b = wl*VT_WS + (c4*4)*104 + j;
        Vt[b        ] = v.x;
        Vt[b + 104  ] = v.y;
        Vt[b + 208  ] = v.z;
        Vt[b + 312  ] = v.w;
    }
    // ---- stage K (384 float2 -> bf16) ----
    #pragma unroll
    for (int i = 0; i < 2; i++) {
        int idx = i*256 + tid;
        if (idx < 384) {
            int wl = idx & 3;
            int j  = idx >> 2;
            float2 kk = Kpn[j*W + w0 + wl];
            Ks[wl*192 + j]      = f2bf(kk.x);
            Ks[wl*192 + 96 + j] = f2bf(kk.y);
        }
    }
    __syncthreads();

    int wl   = tid >> 6;        // wave id 0..3 = column
    int lane = tid & 63;
    int li   = lane & 15;
    int g    = lane >> 4;
    int w    = w0 + wl;
    unsigned short* accCn = accC + (long)n*PX*16;

    #pragma unroll
    for (int ht = 0; ht < 6; ht++) {
        int hglob = ht*16 + li;
        float2 qq = Qpn[hglob*W + w];
        float qx = qq.x * LOG2E, qy = qq.y * LOG2E;
        float m  = fabsf(qx)*g0 + fabsf(qy)*g1;

        v4f acc = {};
        float sp = 0.f;
        #pragma unroll
        for (int kc = 0; kc < 3; kc++) {
            int j0 = kc*32 + g*8;
            v8s bv = *(const v8s*)&Vt[wl*VT_WS + li*104 + j0];
            v8s kxv = *(const v8s*)&Ks[wl*192 + j0];
            v8s kyv = *(const v8s*)&Ks[wl*192 + 96 + j0];
            v8s af;
            #pragma unroll
            for (int e = 0; e < 8; e++) {
                float e2 = bf2f((unsigned short)kxv[e])*qx
                         + bf2f((unsigned short)kyv[e])*qy - m;
                float p = __builtin_amdgcn_exp2f(e2);
                p = (j0 + e == hglob) ? 0.0f : p;
                sp += p;
                af[e] = (short)f2bf(p);
            }
            acc = __builtin_amdgcn_mfma_f32_16x16x32_bf16(af, bv, acc, 0, 0, 0);
        }
        sp += __shfl_xor(sp, 16);
        sp += __shfl_xor(sp, 32);
        if (lane < 16)
            sC[((long)n*H + hglob)*W + w] = sp;

        #pragma unroll
        for (int rr = 0; rr < 4; rr++) {
            int h2 = ht*16 + g*4 + rr;
            accCn[((long)h2*W + w)*16 + li] = f2bf(acc[rr]);
        }
    }
}

// Row (W) attention as MFMA, LDS-free (R19 structure, scalar shift bound).
__global__ __launch_bounds__(256)
void row_attn_kernel(const float2* __restrict__ Qp, const float2* __restrict__ Kp,
                     const unsigned short* __restrict__ Vbp,
                     const float* __restrict__ gm,
                     const unsigned short* __restrict__ accC, const float* __restrict__ sC,
                     const float* __restrict__ xres, long xn_s, long xc_s,
                     float* __restrict__ out, long on_s, long oc_s,
                     const float* __restrict__ gamma_p)
{
    const int chunk = (NIMG*(H/2)) / 8;   // 144
    int bid = blockIdx.x;
    int swz = (bid & 7)*chunk + (bid >> 3);
    int n   = swz / (H/2);
    int h0  = (swz - n*(H/2)) * 2;
    int tid = threadIdx.x;

    const float2* Qpn = Qp + n*PX;
    const float*  Kf  = (const float*)(Kp + n*PX);
    const unsigned short* Vrn = Vbp + (long)n*PX*16;   // [h][c][w]
    float g0 = gm[n*2+0], g1 = gm[n*2+1];

    int wv   = tid >> 6;        // 0..3
    int r    = wv >> 1;
    int half = wv & 1;
    int lane = tid & 63;
    int li   = lane & 15;
    int g    = lane >> 4;
    int h    = h0 + r;

    float qx[6], qy[6], mW[6];
    #pragma unroll
    for (int t = 0; t < 6; t++) {
        int w = (half*6 + t)*16 + li;
        float2 qq = Qpn[h*W + w];
        float lqx = qq.x * LOG2E, lqy = qq.y * LOG2E;
        qx[t] = lqx; qy[t] = lqy;
        mW[t] = fabsf(lqx)*g0 + fabsf(lqy)*g1;
    }

    v4f acc[6] = {};
    float sp[6] = {0.f,0.f,0.f,0.f,0.f,0.f};

    const unsigned short* Vrow = Vrn + (long)h*16*W + (long)li*W;
    const float*          Krow = Kf + (long)h*W*2;

    #pragma unroll
    for (int kc = 0; kc < 6; kc++) {
        int j0 = kc*32 + g*8;
        v8s af = *(const v8s*)(Vrow + j0);                 // 16B contiguous
        const v4f* kp4 = (const v4f*)(Krow + j0*2);
        v4f k0 = kp4[0], k1 = kp4[1], k2 = kp4[2], k3 = kp4[3];
        float kxv[8] = {k0[0],k0[2],k1[0],k1[2],k2[0],k2[2],k3[0],k3[2]};
        float kyv[8] = {k0[1],k0[3],k1[1],k1[3],k2[1],k2[3],k3[1],k3[3]};
        #pragma unroll
        for (int t = 0; t < 6; t++) {
            v8s bf;
            float sl = sp[t];
            #pragma unroll
            for (int e = 0; e < 8; e++) {
                float ev = qx[t]*kxv[e] + qy[t]*kyv[e];
                float p = __builtin_amdgcn_exp2f(ev - mW[t]);
                sl += p;
                bf[e] = (short)f2bf(p);
            }
            sp[t] = sl;
            acc[t] = __builtin_amdgcn_mfma_f32_16x16x32_bf16(af, bf, acc[t], 0, 0, 0);
        }
    }

    float gam = gamma_p[0];
    #pragma unroll
    for (int t = 0; t < 6; t++) {
        float s = sp[t];
        s += __shfl_xor(s, 16);
        s += __shfl_xor(s, 32);
        int w = (half*6 + t)*16 + li;
        float st = sC[((long)n*H + h)*W + w] + s;
        float inv = 1.0f / st;
        long po = (long)h*W + w;
        const unsigned short* cap = accC + (((long)n*H + h)*W + w)*16 + g*4;
        #pragma unroll
        for (int rr = 0; rr < 4; rr++) {
            int c = g*4 + rr;   // D: row = (lane>>4)*4 + reg
            float ac = bf2f(cap[rr]);
            float tot = (acc[t][rr] + ac) * inv;
            out[(long)n*on_s + (long)c*oc_s + po] =
                gam*tot + xres[(long)n*xn_s + (long)c*xc_s + po];
        }
    }
}

extern "C" void kernel_launch(void* const* d_in, const int* in_sizes, int n_in,
                              void* d_out, int out_size, void* d_ws, size_t ws_size,
                              hipStream_t stream) {
    const float* cost = (const float*)d_in[0];   // (1,16,24,96,192)
    const float* q_w  = (const float*)d_in[1];
    const float* q_b  = (const float*)d_in[2];
    const float* k_w  = (const float*)d_in[3];
    const float* k_b  = (const float*)d_in[4];
    const float* v_w  = (const float*)d_in[5];
    const float* v_b  = (const float*)d_in[6];
    const float* gamma= (const float*)d_in[7];
    float* out = (float*)d_out;
    float* ws  = (float*)d_ws;

    float2*  Qp = (float2*)(ws + QP_OFF);
    float2*  Kp = (float2*)(ws + KP_OFF);
    ushort4* Vb4 = (ushort4*)(ws + VB4_OFF);
    unsigned short* Vbp = (unsigned short*)(ws + VBP_OFF);
    float*   gm = ws + GM_OFF;
    float*   sC = ws + SC_OFF;
    unsigned short* aC = (unsigned short*)(ws + ACC_OFF);

    const int qkv_blocks = (NIMG*PX)/256;   // 1728
    const int col_blocks = NIMG*48;         // 1152 (4 columns per block)
    const int row_blocks = NIMG*(H/2);      // 1152

    // zero the per-image |K| maxima (atomicMax targets; re-run every replay)
    hipMemsetAsync(gm, 0, 2*NIMG*sizeof(float), stream);

    // ---- pass 1: x = cost_volume [c][n][h][w] (n stride PX, c stride 24*PX) ----
    qkv_kernel<<<qkv_blocks, 256, 0, stream>>>(
        cost, (long)PX, (long)NIMG*PX,
        q_w, q_b, k_w, k_b, v_w, v_b, Qp, Kp, Vb4, Vbp, gm);
    col_attn_kernel<<<col_blocks, 256, 0, stream>>>(
        Qp, Kp, Vb4, gm, aC, sC);
    row_attn_kernel<<<row_blocks, 256, 0, stream>>>(
        Qp, Kp, Vbp, gm, aC, sC,
        cost, (long)PX, (long)NIMG*PX,
        out,  (long)PX, (long)NIMG*PX,
        gamma);

    // ---- pass 2: x = d_out (same strides; per-thread same-element RMW is safe).
    // gm reuse: pass-2 atomics accumulate onto pass-1 maxima -> still a valid,
    // deterministic upper bound (normalization cancels the shift).
    qkv_kernel<<<qkv_blocks, 256, 0, stream>>>(
        out, (long)PX, (long)NIMG*PX,
        q_w, q_b, k_w, k_b, v_w, v_b, Qp, Kp, Vb4, Vbp, gm);
    col_attn_kernel<<<col_blocks, 256, 0, stream>>>(
        Qp, Kp, Vb4, gm, aC, sC);
    row_attn_kernel<<<row_blocks, 256, 0, stream>>>(
        Qp, Kp, Vbp, gm, aC, sC,
        out, (long)PX, (long)NIMG*PX,
        out, (long)PX, (long)NIMG*PX,
        gamma);
}

// Round 21
// 217.183 us; speedup vs baseline: 1.7741x; 1.7741x over previous
//
#include <hip/hip_runtime.h>

#define C 16
#define NIMG 24
#define H 96
#define W 192
#define PX (H*W)            // 18432
#define LOG2E 1.44269504088896f

typedef float v2f  __attribute__((ext_vector_type(2)));
typedef float v4f  __attribute__((ext_vector_type(4)));
typedef short v8s  __attribute__((ext_vector_type(8)));

// workspace float offsets
#define QP_OFF 0                                // float2 [n][px]
#define KP_OFF (NIMG*PX*2)                      // float2 [n][px]
#define VB4_OFF (2*NIMG*PX*2)                   // ushort4 [n][h][c4][w] (bf16 x4ch)
#define VBP_OFF (VB4_OFF + NIMG*PX*C/2)         // ushort [n][h][c][w] (bf16 planar)
#define GM_OFF  (VBP_OFF + NIMG*PX*C/2)         // 8847360: float gmax [n][2]
#define SC_OFF  (GM_OFF + 128)                  // float s_col [n][h][w]
#define ACC_OFF (SC_OFF + NIMG*PX)              // ushort accC [n][h][w][c]
// end ~ 12.83M floats (~51.3 MB)

__device__ __forceinline__ unsigned short f2bf(float x) {
    union { float f; unsigned u; } v; v.f = x;
    unsigned r = v.u + 0x7fffu + ((v.u >> 16) & 1u);   // RNE
    return (unsigned short)(r >> 16);
}
__device__ __forceinline__ float bf2f(unsigned short u) {
    union { unsigned u; float f; } v; v.u = ((unsigned)u) << 16;
    return v.f;
}

__global__ __launch_bounds__(256)
void qkv_kernel(const float* __restrict__ x, long xn_s, long xc_s,
                const float* __restrict__ qw, const float* __restrict__ qb,
                const float* __restrict__ kw, const float* __restrict__ kb,
                const float* __restrict__ vw, const float* __restrict__ vb,
                float2* __restrict__ Qp, float2* __restrict__ Kp,
                ushort4* __restrict__ Vb4, unsigned short* __restrict__ Vbp)
{
    __shared__ float wq[2*C+2], wk[2*C+2], wv[C*C+C];
    int tid = threadIdx.x;
    if (tid < 2*C) { wq[tid] = qw[tid]; wk[tid] = kw[tid]; }
    if (tid < 2)   { wq[2*C+tid] = qb[tid]; wk[2*C+tid] = kb[tid]; }
    if (tid < C*C) wv[tid] = vw[tid];
    if (tid < C)   wv[C*C+tid] = vb[tid];
    __syncthreads();

    int id = blockIdx.x*256 + tid;        // 0 .. 442367
    int n  = id / PX;
    int p  = id - n*PX;
    int h  = p / W;
    int w  = p - h*W;
    const float* xp = x + (long)n*xn_s + p;

    float xv[C];
    #pragma unroll
    for (int c = 0; c < C; c++) xv[c] = xp[(long)c*xc_s];

    float q0 = wq[2*C], q1 = wq[2*C+1];
    float k0 = wk[2*C], k1 = wk[2*C+1];
    #pragma unroll
    for (int c = 0; c < C; c++) {
        q0 += wq[c]*xv[c];   q1 += wq[C+c]*xv[c];
        k0 += wk[c]*xv[c];   k1 += wk[C+c]*xv[c];
    }
    Qp[id] = make_float2(q0, q1);
    Kp[id] = make_float2(k0, k1);

    float vv[C];
    #pragma unroll
    for (int o = 0; o < C; o++) {
        float a = wv[C*C+o];
        #pragma unroll
        for (int c = 0; c < C; c++) a += wv[o*C+c]*xv[c];
        vv[o] = a;
    }
    unsigned short vb16[C];
    #pragma unroll
    for (int o = 0; o < C; o++) vb16[o] = f2bf(vv[o]);

    // interleaved [n][h][c4][w] (ushort4) for col staging
    #pragma unroll
    for (int c4 = 0; c4 < 4; c4++) {
        ushort4 u;
        u.x = vb16[c4*4+0]; u.y = vb16[c4*4+1];
        u.z = vb16[c4*4+2]; u.w = vb16[c4*4+3];
        Vb4[(((long)n*H + h)*4 + c4)*W + w] = u;
    }
    // planar [n][h][c][w] for row fragment loads
    #pragma unroll
    for (int o = 0; o < C; o++)
        Vbp[(((long)n*H + h)*16 + o)*W + w] = vb16[o];
}

// Per-image |K| maxima: one block per image, no atomics.
__global__ __launch_bounds__(256)
void gmax_kernel(const float2* __restrict__ Kp, float* __restrict__ gm)
{
    __shared__ float red0[4], red1[4];
    int n   = blockIdx.x;
    int tid = threadIdx.x;
    const float2* Kpn = Kp + n*PX;

    float a0 = 0.f, a1 = 0.f;
    for (int i = tid; i < PX; i += 256) {
        float2 k = Kpn[i];
        a0 = fmaxf(a0, fabsf(k.x));
        a1 = fmaxf(a1, fabsf(k.y));
    }
    #pragma unroll
    for (int d = 1; d < 64; d <<= 1) {
        a0 = fmaxf(a0, __shfl_xor(a0, d));
        a1 = fmaxf(a1, __shfl_xor(a1, d));
    }
    if ((tid & 63) == 0) { red0[tid >> 6] = a0; red1[tid >> 6] = a1; }
    __syncthreads();
    if (tid == 0) {
        gm[n*2+0] = fmaxf(fmaxf(red0[0], red0[1]), fmaxf(red0[2], red0[3]));
        gm[n*2+1] = fmaxf(fmaxf(red1[0], red1[1]), fmaxf(red1[2], red1[3]));
    }
}

// Column (H) attention as MFMA (R18 structure, scalar shift bound).
#define VT_WS 1672   // per-w Vt stride in ushorts: 16*104 + 8 pad
__global__ __launch_bounds__(256)
void col_attn_kernel(const float2* __restrict__ Qp, const float2* __restrict__ Kp,
                     const ushort4* __restrict__ Vb4,
                     const float* __restrict__ gm,
                     unsigned short* __restrict__ accC, float* __restrict__ sC)
{
    __shared__ unsigned short Vt[4*VT_WS];      // V^T: [wl][c][j] bf16, j-pad 104
    __shared__ unsigned short Ks[4*2*96];       // K:   [wl][ch][j] bf16

    const int chunk = (NIMG*48) / 8;            // 144 ; 1152 % 8 == 0
    int bid = blockIdx.x;
    int swz = (bid & 7)*chunk + (bid >> 3);
    int n   = swz / 48;
    int wg  = swz - n*48;
    int w0  = wg*4;
    int tid = threadIdx.x;

    const float2* Qpn = Qp + n*PX;
    const float2* Kpn = Kp + n*PX;
    const ushort4* Vbn = Vb4 + (long)n*PX*4;
    float g0 = gm[n*2+0], g1 = gm[n*2+1];

    // ---- stage V^T (1536 ushort4, 6/thread) ----
    #pragma unroll
    for (int i = 0; i < 6; i++) {
        int idx = i*256 + tid;        // 0..1535
        int wl  = idx & 3;
        int c4  = (idx >> 2) & 3;
        int j   = idx >> 4;           // 0..95
        ushort4 v = Vbn[((long)j*4 + c4)*W + w0 + wl];
        int b = wl*VT_WS + (c4*4)*104 + j;
        Vt[b        ] = v.x;
        Vt[b + 104  ] = v.y;
        Vt[b + 208  ] = v.z;
        Vt[b + 312  ] = v.w;
    }
    // ---- stage K (384 float2 -> bf16) ----
    #pragma unroll
    for (int i = 0; i < 2; i++) {
        int idx = i*256 + tid;
        if (idx < 384) {
            int wl = idx & 3;
            int j  = idx >> 2;
            float2 kk = Kpn[j*W + w0 + wl];
            Ks[wl*192 + j]      = f2bf(kk.x);
            Ks[wl*192 + 96 + j] = f2bf(kk.y);
        }
    }
    __syncthreads();

    int wl   = tid >> 6;        // wave id 0..3 = column
    int lane = tid & 63;
    int li   = lane & 15;
    int g    = lane >> 4;
    int w    = w0 + wl;
    unsigned short* accCn = accC + (long)n*PX*16;

    #pragma unroll
    for (int ht = 0; ht < 6; ht++) {
        int hglob = ht*16 + li;
        float2 qq = Qpn[hglob*W + w];
        float qx = qq.x * LOG2E, qy = qq.y * LOG2E;
        float m  = fabsf(qx)*g0 + fabsf(qy)*g1;

        v4f acc = {};
        float sp = 0.f;
        #pragma unroll
        for (int kc = 0; kc < 3; kc++) {
            int j0 = kc*32 + g*8;
            v8s bv = *(const v8s*)&Vt[wl*VT_WS + li*104 + j0];
            v8s kxv = *(const v8s*)&Ks[wl*192 + j0];
            v8s kyv = *(const v8s*)&Ks[wl*192 + 96 + j0];
            v8s af;
            #pragma unroll
            for (int e = 0; e < 8; e++) {
                float e2 = bf2f((unsigned short)kxv[e])*qx
                         + bf2f((unsigned short)kyv[e])*qy - m;
                float p = __builtin_amdgcn_exp2f(e2);
                p = (j0 + e == hglob) ? 0.0f : p;
                sp += p;
                af[e] = (short)f2bf(p);
            }
            acc = __builtin_amdgcn_mfma_f32_16x16x32_bf16(af, bv, acc, 0, 0, 0);
        }
        sp += __shfl_xor(sp, 16);
        sp += __shfl_xor(sp, 32);
        if (lane < 16)
            sC[((long)n*H + hglob)*W + w] = sp;

        #pragma unroll
        for (int rr = 0; rr < 4; rr++) {
            int h2 = ht*16 + g*4 + rr;
            accCn[((long)h2*W + w)*16 + li] = f2bf(acc[rr]);
        }
    }
}

// Row (W) attention as MFMA, LDS-free (R19 structure, scalar shift bound).
__global__ __launch_bounds__(256)
void row_attn_kernel(const float2* __restrict__ Qp, const float2* __restrict__ Kp,
                     const unsigned short* __restrict__ Vbp,
                     const float* __restrict__ gm,
                     const unsigned short* __restrict__ accC, const float* __restrict__ sC,
                     const float* __restrict__ xres, long xn_s, long xc_s,
                     float* __restrict__ out, long on_s, long oc_s,
                     const float* __restrict__ gamma_p)
{
    const int chunk = (NIMG*(H/2)) / 8;   // 144
    int bid = blockIdx.x;
    int swz = (bid & 7)*chunk + (bid >> 3);
    int n   = swz / (H/2);
    int h0  = (swz - n*(H/2)) * 2;
    int tid = threadIdx.x;

    const float2* Qpn = Qp + n*PX;
    const float*  Kf  = (const float*)(Kp + n*PX);
    const unsigned short* Vrn = Vbp + (long)n*PX*16;   // [h][c][w]
    float g0 = gm[n*2+0], g1 = gm[n*2+1];

    int wv   = tid >> 6;        // 0..3
    int r    = wv >> 1;
    int half = wv & 1;
    int lane = tid & 63;
    int li   = lane & 15;
    int g    = lane >> 4;
    int h    = h0 + r;

    float qx[6], qy[6], mW[6];
    #pragma unroll
    for (int t = 0; t < 6; t++) {
        int w = (half*6 + t)*16 + li;
        float2 qq = Qpn[h*W + w];
        float lqx = qq.x * LOG2E, lqy = qq.y * LOG2E;
        qx[t] = lqx; qy[t] = lqy;
        mW[t] = fabsf(lqx)*g0 + fabsf(lqy)*g1;
    }

    v4f acc[6] = {};
    float sp[6] = {0.f,0.f,0.f,0.f,0.f,0.f};

    const unsigned short* Vrow = Vrn + (long)h*16*W + (long)li*W;
    const float*          Krow = Kf + (long)h*W*2;

    #pragma unroll
    for (int kc = 0; kc < 6; kc++) {
        int j0 = kc*32 + g*8;
        v8s af = *(const v8s*)(Vrow + j0);                 // 16B contiguous
        const v4f* kp4 = (const v4f*)(Krow + j0*2);
        v4f k0 = kp4[0], k1 = kp4[1], k2 = kp4[2], k3 = kp4[3];
        float kxv[8] = {k0[0],k0[2],k1[0],k1[2],k2[0],k2[2],k3[0],k3[2]};
        float kyv[8] = {k0[1],k0[3],k1[1],k1[3],k2[1],k2[3],k3[1],k3[3]};
        #pragma unroll
        for (int t = 0; t < 6; t++) {
            v8s bf;
            float sl = sp[t];
            #pragma unroll
            for (int e = 0; e < 8; e++) {
                float ev = qx[t]*kxv[e] + qy[t]*kyv[e];
                float p = __builtin_amdgcn_exp2f(ev - mW[t]);
                sl += p;
                bf[e] = (short)f2bf(p);
            }
            sp[t] = sl;
            acc[t] = __builtin_amdgcn_mfma_f32_16x16x32_bf16(af, bf, acc[t], 0, 0, 0);
        }
    }

    float gam = gamma_p[0];
    #pragma unroll
    for (int t = 0; t < 6; t++) {
        float s = sp[t];
        s += __shfl_xor(s, 16);
        s += __shfl_xor(s, 32);
        int w = (half*6 + t)*16 + li;
        float st = sC[((long)n*H + h)*W + w] + s;
        float inv = 1.0f / st;
        long po = (long)h*W + w;
        const unsigned short* cap = accC + (((long)n*H + h)*W + w)*16 + g*4;
        #pragma unroll
        for (int rr = 0; rr < 4; rr++) {
            int c = g*4 + rr;   // D: row = (lane>>4)*4 + reg
            float ac = bf2f(cap[rr]);
            float tot = (acc[t][rr] + ac) * inv;
            out[(long)n*on_s + (long)c*oc_s + po] =
                gam*tot + xres[(long)n*xn_s + (long)c*xc_s + po];
        }
    }
}

extern "C" void kernel_launch(void* const* d_in, const int* in_sizes, int n_in,
                              void* d_out, int out_size, void* d_ws, size_t ws_size,
                              hipStream_t stream) {
    const float* cost = (const float*)d_in[0];   // (1,16,24,96,192)
    const float* q_w  = (const float*)d_in[1];
    const float* q_b  = (const float*)d_in[2];
    const float* k_w  = (const float*)d_in[3];
    const float* k_b  = (const float*)d_in[4];
    const float* v_w  = (const float*)d_in[5];
    const float* v_b  = (const float*)d_in[6];
    const float* gamma= (const float*)d_in[7];
    float* out = (float*)d_out;
    float* ws  = (float*)d_ws;

    float2*  Qp = (float2*)(ws + QP_OFF);
    float2*  Kp = (float2*)(ws + KP_OFF);
    ushort4* Vb4 = (ushort4*)(ws + VB4_OFF);
    unsigned short* Vbp = (unsigned short*)(ws + VBP_OFF);
    float*   gm = ws + GM_OFF;
    float*   sC = ws + SC_OFF;
    unsigned short* aC = (unsigned short*)(ws + ACC_OFF);

    const int qkv_blocks = (NIMG*PX)/256;   // 1728
    const int col_blocks = NIMG*48;         // 1152 (4 columns per block)
    const int row_blocks = NIMG*(H/2);      // 1152

    // ---- pass 1: x = cost_volume [c][n][h][w] (n stride PX, c stride 24*PX) ----
    qkv_kernel<<<qkv_blocks, 256, 0, stream>>>(
        cost, (long)PX, (long)NIMG*PX,
        q_w, q_b, k_w, k_b, v_w, v_b, Qp, Kp, Vb4, Vbp);
    gmax_kernel<<<NIMG, 256, 0, stream>>>(Kp, gm);
    col_attn_kernel<<<col_blocks, 256, 0, stream>>>(
        Qp, Kp, Vb4, gm, aC, sC);
    row_attn_kernel<<<row_blocks, 256, 0, stream>>>(
        Qp, Kp, Vbp, gm, aC, sC,
        cost, (long)PX, (long)NIMG*PX,
        out,  (long)PX, (long)NIMG*PX,
        gamma);

    // ---- pass 2: x = d_out (same strides; per-thread same-element RMW is safe) ----
    qkv_kernel<<<qkv_blocks, 256, 0, stream>>>(
        out, (long)PX, (long)NIMG*PX,
        q_w, q_b, k_w, k_b, v_w, v_b, Qp, Kp, Vb4, Vbp);
    gmax_kernel<<<NIMG, 256, 0, stream>>>(Kp, gm);
    col_attn_kernel<<<col_blocks, 256, 0, stream>>>(
        Qp, Kp, Vb4, gm, aC, sC);
    row_attn_kernel<<<row_blocks, 256, 0, stream>>>(
        Qp, Kp, Vbp, gm, aC, sC,
        out, (long)PX, (long)NIMG*PX,
        out, (long)PX, (long)NIMG*PX,
        gamma);
}